// Round 12
// baseline (316.941 us; speedup 1.0000x reference)
//
#include <hip/hip_runtime.h>

#define N_NODES 100000
#define N_EDGES 3200000
#define IN_CH 24
#define HIDDEN 64
#define N_CLASSES 16

#define NBUCK 782       // ceil(N_NODES / 128), 128-node buckets
#define CAP 4608        // fixed bucket capacity: mean 4092, sigma 64 -> +8 sigma
#define PTBLOCKS 256
#define PTCHUNK 12500   // part: 256 * 12500 = E
#define NSTRIPS (N_NODES / 16)   // 6250 exact

typedef __attribute__((ext_vector_type(8))) short short8;
typedef __attribute__((ext_vector_type(4))) float float4_;
typedef __attribute__((ext_vector_type(2))) float float2v;

__device__ __forceinline__ unsigned short f2bf(float f) {
    union { float f; unsigned int u; } v; v.f = f;
    unsigned int u = v.u;
    return (unsigned short)((u + 0x7FFFu + ((u >> 16) & 1u)) >> 16);
}
// fp8 e4m3 (OCP on gfx950) pack/unpack via HW converts
__device__ __forceinline__ unsigned short pk_fp8(float a, float b) {
    return (unsigned short)(__builtin_amdgcn_cvt_pk_fp8_f32(a, b, 0, false) & 0xFFFF);
}
__device__ __forceinline__ void accum8(float2v* A, uint2 u) {
    A[0] += __builtin_amdgcn_cvt_pk_f32_fp8(u.x, false);
    A[1] += __builtin_amdgcn_cvt_pk_f32_fp8(u.x, true);
    A[2] += __builtin_amdgcn_cvt_pk_f32_fp8(u.y, false);
    A[3] += __builtin_amdgcn_cvt_pk_f32_fp8(u.y, true);
}

// ---------------- weight prep (+ bucketFill zero) ----------------

__global__ __launch_bounds__(256) void k_prep(const float* __restrict__ W1l,
                                              const float* __restrict__ W1r,
                                              const float* __restrict__ W2l,
                                              const float* __restrict__ W2r,
                                              const float* __restrict__ Wc,
                                              const float* __restrict__ b2,
                                              const float* __restrict__ bc,
                                              unsigned short* __restrict__ Bt1,
                                              unsigned short* __restrict__ Bt2,
                                              float* __restrict__ bias2,
                                              int* __restrict__ bucketFill) {
    int t = threadIdx.x;
    for (int i = t; i < NBUCK; i += 256) bucketFill[i] = 0;
    for (int i = t; i < 64 * 64; i += 256) {
        int o = i >> 6, k = i & 63;
        float v = (k < 24) ? W1r[o * 24 + k] : ((k < 48) ? W1l[o * 24 + k - 24] : 0.f);
        Bt1[i] = f2bf(v);
    }
    for (int i = t; i < 64 * 128; i += 256) {
        int o = i >> 7, k = i & 127;
        float v = (k < 64) ? W2l[o * 64 + k] : W2r[o * 64 + k - 64];
        Bt2[i] = f2bf(v);
    }
    for (int i = t; i < 16 * 128; i += 256) {
        int c = i >> 7, k = i & 127;
        const float* M = (k < 64) ? W2l : W2r;
        int kk = k & 63;
        float s = 0.f;
        for (int j = 0; j < 64; j++) s += Wc[c * 64 + j] * M[j * 64 + kk];
        Bt2[(64 + c) * 128 + k] = f2bf(s);
    }
    for (int i = t; i < 80; i += 256) {
        if (i < 64) bias2[i] = b2[i];
        else {
            int c = i - 64;
            float s = bc[c];
            for (int j = 0; j < 64; j++) s += Wc[c * 64 + j] * b2[j];
            bias2[i] = s;
        }
    }
}

// ---------------- bucket partition (fixed-capacity; no global scan) --------

__global__ __launch_bounds__(1024) void k_part(const int* __restrict__ src,
                                               const int* __restrict__ dst,
                                               int* __restrict__ bucketFill,
                                               unsigned int* __restrict__ pedges) {
    __shared__ int cntL[NBUCK];
    __shared__ int baseL[NBUCK];
    int t = threadIdx.x;
    int cbeg = blockIdx.x * PTCHUNK;
    int d[13], s[13];
#pragma unroll
    for (int k = 0; k < 13; k++) {
        int o = k * 1024 + t;
        bool ok = o < PTCHUNK;
        d[k] = ok ? dst[cbeg + o] : -1;
        s[k] = ok ? src[cbeg + o] : 0;
    }
    for (int i = t; i < NBUCK; i += 1024) cntL[i] = 0;
    __syncthreads();
#pragma unroll
    for (int k = 0; k < 13; k++)
        if (d[k] >= 0) atomicAdd(&cntL[d[k] >> 7], 1);
    __syncthreads();
    for (int i = t; i < NBUCK; i += 1024) {
        int c = cntL[i];
        if (c) baseL[i] = i * CAP + atomicAdd(&bucketFill[i], c);
        cntL[i] = 0;
    }
    __syncthreads();
#pragma unroll
    for (int k = 0; k < 13; k++)
        if (d[k] >= 0) {
            int bk = d[k] >> 7;
            int r = atomicAdd(&cntL[bk], 1);
            pedges[baseL[bk] + r] = ((unsigned int)(d[k] & 127) << 17) | (unsigned int)s[k];
        }
}

// per-bucket finalize: sorted srcs + per-node (beg,end). int LDS atomics only
// (FLOAT LDS atomics are catastrophic on gfx950 — R9: 29x regression)
__global__ __launch_bounds__(1024) void k_bucket(const unsigned int* __restrict__ pedges,
                                                 const int* __restrict__ bucketFill,
                                                 int2* __restrict__ begend,
                                                 int* __restrict__ srcs, int N) {
    __shared__ int ncnt[128];
    __shared__ int sps[128];
    int b = blockIdx.x;
    int t = threadIdx.x;
    int eb0 = b * CAP;
    int m = bucketFill[b];
    unsigned int v[5];
#pragma unroll
    for (int k = 0; k < 5; k++) {
        int o = k * 1024 + t;
        v[k] = (o < m) ? pedges[eb0 + o] : 0xFFFFFFFFu;
    }
    if (t < 128) ncnt[t] = 0;
    __syncthreads();
#pragma unroll
    for (int k = 0; k < 5; k++)
        if (v[k] != 0xFFFFFFFFu) atomicAdd(&ncnt[v[k] >> 17], 1);
    __syncthreads();
    int myc = (t < 128) ? ncnt[t] : 0;
    int val = myc;
    if (t < 128) sps[t] = val;
    __syncthreads();
    for (int off = 1; off < 128; off <<= 1) {
        int vv = (t >= off && t < 128) ? sps[t - off] : 0;
        __syncthreads();
        if (t < 128) { val += vv; sps[t] = val; }
        __syncthreads();
    }
    int mybase = val - myc;
    int node = b * 128 + t;
    if (t < 128 && node < N) {
        int2 be; be.x = eb0 + mybase; be.y = eb0 + mybase + myc;
        begend[node] = be;
    }
    if (t < 128) { sps[t] = mybase; ncnt[t] = 0; }
    // zero slack tail so masked tail gathers read node 0 (cnt+32 <= CAP)
    if (t < 32) srcs[eb0 + m + t] = 0;
    __syncthreads();
#pragma unroll
    for (int k = 0; k < 5; k++)
        if (v[k] != 0xFFFFFFFFu) {
            unsigned int nl = v[k] >> 17;
            int r = atomicAdd(&ncnt[nl], 1);
            srcs[eb0 + sps[nl] + r] = (int)(v[k] & 0x1FFFF);
        }
}

// x fp32 -> A1 bf16 x-zone + zeroed pad (pedges aliases A1u/X8 — Inf/NaN hazard)
//        -> X8 fp8 rows (32 B: 24 real + 8 zero pad)
__global__ __launch_bounds__(256) void k_castx(const float* __restrict__ x,
                                               unsigned int* __restrict__ A1u,
                                               unsigned short* __restrict__ X8s) {
    int gid = blockIdx.x * 256 + threadIdx.x;
    if (gid >= N_NODES * 16) return;
    int n = gid >> 4, kp = gid & 15;
    if (kp < 12) {
        const float2 v = *(const float2*)(x + n * 24 + kp * 2);
        A1u[n * 32 + kp] = (unsigned int)f2bf(v.x) | ((unsigned int)f2bf(v.y) << 16);
        X8s[n * 16 + kp] = pk_fp8(v.x, v.y);
    } else {
        int p = kp - 12;
        uint2 z; z.x = 0u; z.y = 0u;
        *(uint2*)(A1u + n * 32 + 24 + p * 2) = z;
        X8s[n * 16 + kp] = 0;
    }
}

// ---------------- aggregations (fp8 gather, 32B L2-resident tables) --------

// agg1: gather 32B X8 rows, 4 lanes/edge (uint2 = 8 fp8), 32 edges/iter
__global__ __launch_bounds__(256) void k_agg1(const unsigned int* __restrict__ X8u,
                                              const int2* __restrict__ begend,
                                              const int* __restrict__ srcs,
                                              unsigned int* __restrict__ A1w, int N) {
    int node = (blockIdx.x * 256 + threadIdx.x) >> 6;
    int lane = threadIdx.x & 63;
    if (node >= N) return;
    int2 be = begend[node];
    int b = be.x, e = be.y;
    int grp = lane >> 2;    // 0..15 edge slot
    int sub = lane & 3;     // 8B chunk of 32B row
    const unsigned int* basep = X8u + sub * 2;
    float2v A[4] = {{0.f, 0.f}, {0.f, 0.f}, {0.f, 0.f}, {0.f, 0.f}};
    int nfull = (e - b) & ~31;
    int j = b;
    for (; j < b + nfull; j += 32) {
        int s0 = srcs[j + grp];
        int s1 = srcs[j + 16 + grp];
        uint2 u0 = *(const uint2*)(basep + (size_t)s0 * 8);
        uint2 u1 = *(const uint2*)(basep + (size_t)s1 * 8);
        accum8(A, u0);
        accum8(A, u1);
    }
    if (j < e) {
        int j0 = j + grp, j1 = j0 + 16;
        int s0 = srcs[j0], s1 = srcs[j1];
        uint2 u0 = *(const uint2*)(basep + (size_t)s0 * 8);
        uint2 u1 = *(const uint2*)(basep + (size_t)s1 * 8);
        if (j0 >= e) { u0.x = 0; u0.y = 0; }
        if (j1 >= e) { u1.x = 0; u1.y = 0; }
        accum8(A, u0);
        accum8(A, u1);
    }
#pragma unroll
    for (int m = 4; m <= 32; m <<= 1) {
#pragma unroll
        for (int q = 0; q < 4; q++) {
            A[q].x += __shfl_xor(A[q].x, m, 64);
            A[q].y += __shfl_xor(A[q].y, m, 64);
        }
    }
    if (lane < 4) {
        // sub==3 sums X8 pad zeros -> writes zeros to pad dwords 24..27
        float inv = 1.f / (float)max(e - b, 1);
        uint4 o;
        o.x = (unsigned int)f2bf(A[0].x * inv) | ((unsigned int)f2bf(A[0].y * inv) << 16);
        o.y = (unsigned int)f2bf(A[1].x * inv) | ((unsigned int)f2bf(A[1].y * inv) << 16);
        o.z = (unsigned int)f2bf(A[2].x * inv) | ((unsigned int)f2bf(A[2].y * inv) << 16);
        o.w = (unsigned int)f2bf(A[3].x * inv) | ((unsigned int)f2bf(A[3].y * inv) << 16);
        *(uint4*)(A1w + (size_t)node * 32 + 12 + sub * 4) = o;
    }
}

// agg2 slice pass: gather 32B slice-table rows (channels [32*slice,32*slice+32)),
// 4 lanes/edge, 32 edges/iter; out at dword offset outOff in the mean zone
__global__ __launch_bounds__(256) void k_agg2s(const unsigned int* __restrict__ T8u,
                                               const int2* __restrict__ begend,
                                               const int* __restrict__ srcs,
                                               unsigned int* __restrict__ A2w,
                                               int outOff, int N) {
    int node = (blockIdx.x * 256 + threadIdx.x) >> 6;
    int lane = threadIdx.x & 63;
    if (node >= N) return;
    int2 be = begend[node];
    int b = be.x, e = be.y;
    int grp = lane >> 2;
    int sub = lane & 3;
    const unsigned int* basep = T8u + sub * 2;
    float2v A[4] = {{0.f, 0.f}, {0.f, 0.f}, {0.f, 0.f}, {0.f, 0.f}};
    int nfull = (e - b) & ~31;
    int j = b;
    for (; j < b + nfull; j += 32) {
        int s0 = srcs[j + grp];
        int s1 = srcs[j + 16 + grp];
        uint2 u0 = *(const uint2*)(basep + (size_t)s0 * 8);
        uint2 u1 = *(const uint2*)(basep + (size_t)s1 * 8);
        accum8(A, u0);
        accum8(A, u1);
    }
    if (j < e) {
        int j0 = j + grp, j1 = j0 + 16;
        int s0 = srcs[j0], s1 = srcs[j1];
        uint2 u0 = *(const uint2*)(basep + (size_t)s0 * 8);
        uint2 u1 = *(const uint2*)(basep + (size_t)s1 * 8);
        if (j0 >= e) { u0.x = 0; u0.y = 0; }
        if (j1 >= e) { u1.x = 0; u1.y = 0; }
        accum8(A, u0);
        accum8(A, u1);
    }
#pragma unroll
    for (int m = 4; m <= 32; m <<= 1) {
#pragma unroll
        for (int q = 0; q < 4; q++) {
            A[q].x += __shfl_xor(A[q].x, m, 64);
            A[q].y += __shfl_xor(A[q].y, m, 64);
        }
    }
    if (lane < 4) {
        float inv = 1.f / (float)max(e - b, 1);
        uint4 o;
        o.x = (unsigned int)f2bf(A[0].x * inv) | ((unsigned int)f2bf(A[0].y * inv) << 16);
        o.y = (unsigned int)f2bf(A[1].x * inv) | ((unsigned int)f2bf(A[1].y * inv) << 16);
        o.z = (unsigned int)f2bf(A[2].x * inv) | ((unsigned int)f2bf(A[2].y * inv) << 16);
        o.w = (unsigned int)f2bf(A[3].x * inv) | ((unsigned int)f2bf(A[3].y * inv) << 16);
        *(uint4*)(A2w + (size_t)node * 64 + outOff + sub * 4) = o;
    }
}

// ---------------- MFMA GEMMs (no LDS; B^T in registers) ----------------

// h = relu(A1 @ Bt1^T + b1): bf16 into A2 h-half AND fp8 into slice tables
__global__ __launch_bounds__(256) void k_gemm1(const unsigned short* __restrict__ A1,
                                               const unsigned short* __restrict__ Bt1,
                                               const float* __restrict__ b1,
                                               unsigned short* __restrict__ A2s,
                                               unsigned char* __restrict__ H8a,
                                               unsigned char* __restrict__ H8b) {
    int wave = (blockIdx.x * 256 + threadIdx.x) >> 6;
    int lane = threadIdx.x & 63;
    int m = lane & 15, quad = lane >> 4;
    if (wave >= NSTRIPS) return;
    short8 bf[4][2];
#pragma unroll
    for (int t = 0; t < 4; t++)
#pragma unroll
        for (int s = 0; s < 2; s++)
            bf[t][s] = *(const short8*)(Bt1 + (t * 16 + m) * 64 + s * 32 + quad * 8);
    float bias[4];
#pragma unroll
    for (int t = 0; t < 4; t++) bias[t] = b1[t * 16 + m];

    int row0 = wave * 16;
    short8 a0 = *(const short8*)(A1 + (row0 + m) * 64 + quad * 8);
    short8 a1 = *(const short8*)(A1 + (row0 + m) * 64 + 32 + quad * 8);
    float4_ acc[4];
#pragma unroll
    for (int t = 0; t < 4; t++) {
        float4_ c = {0.f, 0.f, 0.f, 0.f};
        c = __builtin_amdgcn_mfma_f32_16x16x32_bf16(a0, bf[t][0], c, 0, 0, 0);
        c = __builtin_amdgcn_mfma_f32_16x16x32_bf16(a1, bf[t][1], c, 0, 0, 0);
        acc[t] = c;
    }
#pragma unroll
    for (int t = 0; t < 4; t++) {
        int col = t * 16 + m;
        unsigned char* H8 = (t < 2) ? H8a : H8b;
        int hcol = (t < 2) ? col : col - 32;
#pragma unroll
        for (int r = 0; r < 4; r++) {
            int row = row0 + quad * 4 + r;
            float v = fmaxf(acc[t][r] + bias[t], 0.f);
            A2s[row * 128 + 64 + col] = f2bf(v);
            H8[row * 32 + hcol] =
                (unsigned char)(__builtin_amdgcn_cvt_pk_fp8_f32(v, 0.f, 0, false) & 0xFF);
        }
    }
}

__global__ __launch_bounds__(256) void k_gemm2(const unsigned short* __restrict__ Bt2,
                                               const float* __restrict__ bias2,
                                               unsigned short* A2s,
                                               float* logits) {
    int wave = (blockIdx.x * 256 + threadIdx.x) >> 6;
    int lane = threadIdx.x & 63;
    int m = lane & 15, quad = lane >> 4;
    if (wave >= NSTRIPS) return;
    short8 bf[5][4];
#pragma unroll
    for (int t = 0; t < 5; t++)
#pragma unroll
        for (int s = 0; s < 4; s++)
            bf[t][s] = *(const short8*)(Bt2 + (t * 16 + m) * 128 + s * 32 + quad * 8);
    float bias[5];
#pragma unroll
    for (int t = 0; t < 5; t++) bias[t] = bias2[t * 16 + m];

    int row0 = wave * 16;
    short8 a[4];
#pragma unroll
    for (int s = 0; s < 4; s++)
        a[s] = *(const short8*)(A2s + (row0 + m) * 128 + s * 32 + quad * 8);
    float4_ acc[5];
#pragma unroll
    for (int t = 0; t < 5; t++) {
        float4_ c = {0.f, 0.f, 0.f, 0.f};
#pragma unroll
        for (int s = 0; s < 4; s++)
            c = __builtin_amdgcn_mfma_f32_16x16x32_bf16(a[s], bf[t][s], c, 0, 0, 0);
        acc[t] = c;
    }
    float* embp = (float*)A2s;
#pragma unroll
    for (int t = 0; t < 4; t++) {
#pragma unroll
        for (int r = 0; r < 4; r++) {
            int row = row0 + quad * 4 + r;
            embp[row * 64 + t * 16 + m] = acc[t][r] + bias[t];
        }
    }
#pragma unroll
    for (int r = 0; r < 4; r++) {
        int row = row0 + quad * 4 + r;
        logits[row * 16 + m] = acc[4][r] + bias[4];
    }
}

// ---------------- launch ----------------

extern "C" void kernel_launch(void* const* d_in, const int* in_sizes, int n_in,
                              void* d_out, int out_size, void* d_ws, size_t ws_size,
                              hipStream_t stream) {
    const float* x = (const float*)d_in[0];
    const int* edge = (const int*)d_in[1];
    const int* srcIdx = edge;
    const int* dstIdx = edge + N_EDGES;
    const float* W1l = (const float*)d_in[2];
    const float* b1  = (const float*)d_in[3];
    const float* W1r = (const float*)d_in[4];
    const float* W2l = (const float*)d_in[5];
    const float* b2  = (const float*)d_in[6];
    const float* W2r = (const float*)d_in[7];
    const float* Wc  = (const float*)d_in[8];
    const float* bc  = (const float*)d_in[9];

    float* logits = (float*)d_out;
    unsigned short* A2s = (unsigned short*)((float*)d_out + (size_t)N_NODES * N_CLASSES);
    unsigned int* A2u = (unsigned int*)A2s;

    char* w = (char*)d_ws;
    auto carve = [&](size_t bytes) {
        char* p = w;
        w += (bytes + 255) & ~(size_t)255;
        return p;
    };
    int2* begend         = (int2*)carve((size_t)N_NODES * sizeof(int2));
    int* srcs            = (int*)carve((size_t)NBUCK * CAP * sizeof(int));
    unsigned int* A1u    = (unsigned int*)carve((size_t)N_NODES * 32 * sizeof(unsigned int));
    unsigned short* X8s  = (unsigned short*)carve((size_t)N_NODES * 32);   // fp8 x, 32B rows
    unsigned char* H8a   = (unsigned char*)carve((size_t)N_NODES * 32);    // fp8 h ch 0..31
    unsigned char* H8b   = (unsigned char*)carve((size_t)N_NODES * 32);    // fp8 h ch 32..63
    int* bucketFill      = (int*)carve(NBUCK * sizeof(int));
    unsigned short* Bt1  = (unsigned short*)carve(64 * 64 * sizeof(unsigned short));
    unsigned short* Bt2  = (unsigned short*)carve(80 * 128 * sizeof(unsigned short));
    float* bias2         = (float*)carve(80 * sizeof(float));

    // pedges (14.4 MB) aliases A1u (12.8 MB) + start of X8s; both are written
    // only AFTER k_bucket has consumed pedges
    unsigned int* pedges = (unsigned int*)A1u;
    unsigned short* A1s = (unsigned short*)A1u;
    unsigned int* X8u = (unsigned int*)X8s;
    unsigned int* H8au = (unsigned int*)H8a;
    unsigned int* H8bu = (unsigned int*)H8b;

    k_prep<<<1, 256, 0, stream>>>(W1l, W1r, W2l, W2r, Wc, b2, bc, Bt1, Bt2, bias2,
                                  bucketFill);
    k_part<<<PTBLOCKS, 1024, 0, stream>>>(srcIdx, dstIdx, bucketFill, pedges);
    k_bucket<<<NBUCK, 1024, 0, stream>>>(pedges, bucketFill, begend, srcs, N_NODES);

    k_castx<<<(N_NODES * 16 + 255) / 256, 256, 0, stream>>>(x, A1u, X8s);
    int agrid = (N_NODES * 64 + 255) / 256;
    k_agg1<<<agrid, 256, 0, stream>>>(X8u, begend, srcs, A1u, N_NODES);
    k_gemm1<<<(NSTRIPS + 3) / 4, 256, 0, stream>>>(A1s, Bt1, b1, A2s, H8a, H8b);
    k_agg2s<<<agrid, 256, 0, stream>>>(H8au, begend, srcs, A2u, 0, N_NODES);
    k_agg2s<<<agrid, 256, 0, stream>>>(H8bu, begend, srcs, A2u, 16, N_NODES);
    k_gemm2<<<(NSTRIPS + 3) / 4, 256, 0, stream>>>(Bt2, bias2, A2s, logits);
}

// Round 13
// 285.753 us; speedup vs baseline: 1.1091x; 1.1091x over previous
//
#include <hip/hip_runtime.h>

#define N_NODES 100000
#define N_EDGES 3200000
#define IN_CH 24
#define HIDDEN 64
#define N_CLASSES 16

#define NBUCK 782       // ceil(N_NODES / 128), 128-node buckets
#define CAP 4608        // fixed bucket capacity: mean 4092, sigma 64 -> +8 sigma
#define PTBLOCKS 256
#define PTCHUNK 12500   // part: 256 * 12500 = E
#define NSTRIPS (N_NODES / 16)   // 6250 exact

typedef __attribute__((ext_vector_type(8))) short short8;
typedef __attribute__((ext_vector_type(4))) float float4_;
typedef __attribute__((ext_vector_type(2))) float float2v;

__device__ __forceinline__ unsigned short f2bf(float f) {
    union { float f; unsigned int u; } v; v.f = f;
    unsigned int u = v.u;
    return (unsigned short)((u + 0x7FFFu + ((u >> 16) & 1u)) >> 16);
}
// fp8 e4m3 (OCP on gfx950) pack/unpack via HW converts
__device__ __forceinline__ unsigned short pk_fp8(float a, float b) {
    return (unsigned short)(__builtin_amdgcn_cvt_pk_fp8_f32(a, b, 0, false) & 0xFFFF);
}
__device__ __forceinline__ void accum8(float2v* A, uint2 u) {
    A[0] += __builtin_amdgcn_cvt_pk_f32_fp8(u.x, false);
    A[1] += __builtin_amdgcn_cvt_pk_f32_fp8(u.x, true);
    A[2] += __builtin_amdgcn_cvt_pk_f32_fp8(u.y, false);
    A[3] += __builtin_amdgcn_cvt_pk_f32_fp8(u.y, true);
}

// ---------------- weight prep (+ bucketFill zero) ----------------

__global__ __launch_bounds__(256) void k_prep(const float* __restrict__ W1l,
                                              const float* __restrict__ W1r,
                                              const float* __restrict__ W2l,
                                              const float* __restrict__ W2r,
                                              const float* __restrict__ Wc,
                                              const float* __restrict__ b2,
                                              const float* __restrict__ bc,
                                              unsigned short* __restrict__ Bt1,
                                              unsigned short* __restrict__ Bt2,
                                              float* __restrict__ bias2,
                                              int* __restrict__ bucketFill) {
    int t = threadIdx.x;
    for (int i = t; i < NBUCK; i += 256) bucketFill[i] = 0;
    for (int i = t; i < 64 * 64; i += 256) {
        int o = i >> 6, k = i & 63;
        float v = (k < 24) ? W1r[o * 24 + k] : ((k < 48) ? W1l[o * 24 + k - 24] : 0.f);
        Bt1[i] = f2bf(v);
    }
    for (int i = t; i < 64 * 128; i += 256) {
        int o = i >> 7, k = i & 127;
        float v = (k < 64) ? W2l[o * 64 + k] : W2r[o * 64 + k - 64];
        Bt2[i] = f2bf(v);
    }
    for (int i = t; i < 16 * 128; i += 256) {
        int c = i >> 7, k = i & 127;
        const float* M = (k < 64) ? W2l : W2r;
        int kk = k & 63;
        float s = 0.f;
        for (int j = 0; j < 64; j++) s += Wc[c * 64 + j] * M[j * 64 + kk];
        Bt2[(64 + c) * 128 + k] = f2bf(s);
    }
    for (int i = t; i < 80; i += 256) {
        if (i < 64) bias2[i] = b2[i];
        else {
            int c = i - 64;
            float s = bc[c];
            for (int j = 0; j < 64; j++) s += Wc[c * 64 + j] * b2[j];
            bias2[i] = s;
        }
    }
}

// ---------------- bucket partition (fixed-capacity; no global scan) --------

__global__ __launch_bounds__(1024) void k_part(const int* __restrict__ src,
                                               const int* __restrict__ dst,
                                               int* __restrict__ bucketFill,
                                               unsigned int* __restrict__ pedges) {
    __shared__ int cntL[NBUCK];
    __shared__ int baseL[NBUCK];
    int t = threadIdx.x;
    int cbeg = blockIdx.x * PTCHUNK;
    int d[13], s[13];
#pragma unroll
    for (int k = 0; k < 13; k++) {
        int o = k * 1024 + t;
        bool ok = o < PTCHUNK;
        d[k] = ok ? dst[cbeg + o] : -1;
        s[k] = ok ? src[cbeg + o] : 0;
    }
    for (int i = t; i < NBUCK; i += 1024) cntL[i] = 0;
    __syncthreads();
#pragma unroll
    for (int k = 0; k < 13; k++)
        if (d[k] >= 0) atomicAdd(&cntL[d[k] >> 7], 1);
    __syncthreads();
    for (int i = t; i < NBUCK; i += 1024) {
        int c = cntL[i];
        if (c) baseL[i] = i * CAP + atomicAdd(&bucketFill[i], c);
        cntL[i] = 0;
    }
    __syncthreads();
#pragma unroll
    for (int k = 0; k < 13; k++)
        if (d[k] >= 0) {
            int bk = d[k] >> 7;
            int r = atomicAdd(&cntL[bk], 1);
            pedges[baseL[bk] + r] = ((unsigned int)(d[k] & 127) << 17) | (unsigned int)s[k];
        }
}

// per-bucket finalize: sorted srcs + per-node (beg,end). int LDS atomics only
// (FLOAT LDS atomics are catastrophic on gfx950 — R9: 29x regression)
__global__ __launch_bounds__(1024) void k_bucket(const unsigned int* __restrict__ pedges,
                                                 const int* __restrict__ bucketFill,
                                                 int2* __restrict__ begend,
                                                 int* __restrict__ srcs, int N) {
    __shared__ int ncnt[128];
    __shared__ int sps[128];
    int b = blockIdx.x;
    int t = threadIdx.x;
    int eb0 = b * CAP;
    int m = bucketFill[b];
    unsigned int v[5];
#pragma unroll
    for (int k = 0; k < 5; k++) {
        int o = k * 1024 + t;
        v[k] = (o < m) ? pedges[eb0 + o] : 0xFFFFFFFFu;
    }
    if (t < 128) ncnt[t] = 0;
    __syncthreads();
#pragma unroll
    for (int k = 0; k < 5; k++)
        if (v[k] != 0xFFFFFFFFu) atomicAdd(&ncnt[v[k] >> 17], 1);
    __syncthreads();
    int myc = (t < 128) ? ncnt[t] : 0;
    int val = myc;
    if (t < 128) sps[t] = val;
    __syncthreads();
    for (int off = 1; off < 128; off <<= 1) {
        int vv = (t >= off && t < 128) ? sps[t - off] : 0;
        __syncthreads();
        if (t < 128) { val += vv; sps[t] = val; }
        __syncthreads();
    }
    int mybase = val - myc;
    int node = b * 128 + t;
    if (t < 128 && node < N) {
        int2 be; be.x = eb0 + mybase; be.y = eb0 + mybase + myc;
        begend[node] = be;
    }
    if (t < 128) { sps[t] = mybase; ncnt[t] = 0; }
    // zero slack tail so masked tail gathers read node 0 (cnt+32 <= CAP)
    if (t < 32) srcs[eb0 + m + t] = 0;
    __syncthreads();
#pragma unroll
    for (int k = 0; k < 5; k++)
        if (v[k] != 0xFFFFFFFFu) {
            unsigned int nl = v[k] >> 17;
            int r = atomicAdd(&ncnt[nl], 1);
            srcs[eb0 + sps[nl] + r] = (int)(v[k] & 0x1FFFF);
        }
}

// x fp32 -> A1 bf16 x-zone + zeroed pad (pedges aliases A1u/X8 — Inf/NaN hazard)
//        -> X8 fp8 rows (32 B: 24 real + 8 zero pad)
__global__ __launch_bounds__(256) void k_castx(const float* __restrict__ x,
                                               unsigned int* __restrict__ A1u,
                                               unsigned short* __restrict__ X8s) {
    int gid = blockIdx.x * 256 + threadIdx.x;
    if (gid >= N_NODES * 16) return;
    int n = gid >> 4, kp = gid & 15;
    if (kp < 12) {
        const float2 v = *(const float2*)(x + n * 24 + kp * 2);
        A1u[n * 32 + kp] = (unsigned int)f2bf(v.x) | ((unsigned int)f2bf(v.y) << 16);
        X8s[n * 16 + kp] = pk_fp8(v.x, v.y);
    } else {
        int p = kp - 12;
        uint2 z; z.x = 0u; z.y = 0u;
        *(uint2*)(A1u + n * 32 + 24 + p * 2) = z;
        X8s[n * 16 + kp] = 0;
    }
}

// ---------------- aggregations (fp8 gather tables) ----------------

// agg1: gather 32B X8 rows, 4 lanes/edge (uint2 = 8 fp8), 32 edges/iter
__global__ __launch_bounds__(256) void k_agg1(const unsigned int* __restrict__ X8u,
                                              const int2* __restrict__ begend,
                                              const int* __restrict__ srcs,
                                              unsigned int* __restrict__ A1w, int N) {
    int node = (blockIdx.x * 256 + threadIdx.x) >> 6;
    int lane = threadIdx.x & 63;
    if (node >= N) return;
    int2 be = begend[node];
    int b = be.x, e = be.y;
    int grp = lane >> 2;    // 0..15 edge slot
    int sub = lane & 3;     // 8B chunk of 32B row
    const unsigned int* basep = X8u + sub * 2;
    float2v A[4] = {{0.f, 0.f}, {0.f, 0.f}, {0.f, 0.f}, {0.f, 0.f}};
    int nfull = (e - b) & ~31;
    int j = b;
    for (; j < b + nfull; j += 32) {
        int s0 = srcs[j + grp];
        int s1 = srcs[j + 16 + grp];
        uint2 u0 = *(const uint2*)(basep + (size_t)s0 * 8);
        uint2 u1 = *(const uint2*)(basep + (size_t)s1 * 8);
        accum8(A, u0);
        accum8(A, u1);
    }
    if (j < e) {
        int j0 = j + grp, j1 = j0 + 16;
        int s0 = srcs[j0], s1 = srcs[j1];
        uint2 u0 = *(const uint2*)(basep + (size_t)s0 * 8);
        uint2 u1 = *(const uint2*)(basep + (size_t)s1 * 8);
        if (j0 >= e) { u0.x = 0; u0.y = 0; }
        if (j1 >= e) { u1.x = 0; u1.y = 0; }
        accum8(A, u0);
        accum8(A, u1);
    }
#pragma unroll
    for (int m = 4; m <= 32; m <<= 1) {
#pragma unroll
        for (int q = 0; q < 4; q++) {
            A[q].x += __shfl_xor(A[q].x, m, 64);
            A[q].y += __shfl_xor(A[q].y, m, 64);
        }
    }
    if (lane < 4) {
        // sub==3 sums X8 pad zeros -> writes zeros to pad dwords 24..27
        float inv = 1.f / (float)max(e - b, 1);
        uint4 o;
        o.x = (unsigned int)f2bf(A[0].x * inv) | ((unsigned int)f2bf(A[0].y * inv) << 16);
        o.y = (unsigned int)f2bf(A[1].x * inv) | ((unsigned int)f2bf(A[1].y * inv) << 16);
        o.z = (unsigned int)f2bf(A[2].x * inv) | ((unsigned int)f2bf(A[2].y * inv) << 16);
        o.w = (unsigned int)f2bf(A[3].x * inv) | ((unsigned int)f2bf(A[3].y * inv) << 16);
        *(uint4*)(A1w + (size_t)node * 32 + 12 + sub * 4) = o;
    }
}

// agg2: gather 64B H8 rows, 8 lanes/edge (uint2 = 8 fp8), 32 edges/iter
__global__ __launch_bounds__(256) void k_agg2(const unsigned int* __restrict__ H8u,
                                              const int2* __restrict__ begend,
                                              const int* __restrict__ srcs,
                                              unsigned int* __restrict__ A2w, int N) {
    int node = (blockIdx.x * 256 + threadIdx.x) >> 6;
    int lane = threadIdx.x & 63;
    if (node >= N) return;
    int2 be = begend[node];
    int b = be.x, e = be.y;
    int grp = lane >> 3;    // 0..7 edge slot
    int sub = lane & 7;     // 8B chunk of 64B row
    const unsigned int* basep = H8u + sub * 2;
    float2v A[4] = {{0.f, 0.f}, {0.f, 0.f}, {0.f, 0.f}, {0.f, 0.f}};
    int nfull = (e - b) & ~31;
    int j = b;
    for (; j < b + nfull; j += 32) {
        int s0 = srcs[j + grp];
        int s1 = srcs[j + 8 + grp];
        int s2 = srcs[j + 16 + grp];
        int s3 = srcs[j + 24 + grp];
        uint2 u0 = *(const uint2*)(basep + (size_t)s0 * 16);
        uint2 u1 = *(const uint2*)(basep + (size_t)s1 * 16);
        uint2 u2 = *(const uint2*)(basep + (size_t)s2 * 16);
        uint2 u3 = *(const uint2*)(basep + (size_t)s3 * 16);
        accum8(A, u0);
        accum8(A, u1);
        accum8(A, u2);
        accum8(A, u3);
    }
    if (j < e) {
        int j0 = j + grp, j1 = j0 + 8, j2 = j0 + 16, j3 = j0 + 24;
        int s0 = srcs[j0], s1 = srcs[j1], s2 = srcs[j2], s3 = srcs[j3];
        uint2 u0 = *(const uint2*)(basep + (size_t)s0 * 16);
        uint2 u1 = *(const uint2*)(basep + (size_t)s1 * 16);
        uint2 u2 = *(const uint2*)(basep + (size_t)s2 * 16);
        uint2 u3 = *(const uint2*)(basep + (size_t)s3 * 16);
        if (j0 >= e) { u0.x = 0; u0.y = 0; }
        if (j1 >= e) { u1.x = 0; u1.y = 0; }
        if (j2 >= e) { u2.x = 0; u2.y = 0; }
        if (j3 >= e) { u3.x = 0; u3.y = 0; }
        accum8(A, u0);
        accum8(A, u1);
        accum8(A, u2);
        accum8(A, u3);
    }
#pragma unroll
    for (int m = 8; m <= 32; m <<= 1) {
#pragma unroll
        for (int q = 0; q < 4; q++) {
            A[q].x += __shfl_xor(A[q].x, m, 64);
            A[q].y += __shfl_xor(A[q].y, m, 64);
        }
    }
    if (lane < 8) {
        float inv = 1.f / (float)max(e - b, 1);
        uint4 o;
        o.x = (unsigned int)f2bf(A[0].x * inv) | ((unsigned int)f2bf(A[0].y * inv) << 16);
        o.y = (unsigned int)f2bf(A[1].x * inv) | ((unsigned int)f2bf(A[1].y * inv) << 16);
        o.z = (unsigned int)f2bf(A[2].x * inv) | ((unsigned int)f2bf(A[2].y * inv) << 16);
        o.w = (unsigned int)f2bf(A[3].x * inv) | ((unsigned int)f2bf(A[3].y * inv) << 16);
        *(uint4*)(A2w + (size_t)node * 64 + sub * 4) = o;
    }
}

// ---------------- MFMA GEMMs (no LDS; B^T in registers) ----------------

// h = relu(A1 @ Bt1^T + b1): bf16 into A2 h-half AND fp8 into H8 (64B rows)
__global__ __launch_bounds__(256) void k_gemm1(const unsigned short* __restrict__ A1,
                                               const unsigned short* __restrict__ Bt1,
                                               const float* __restrict__ b1,
                                               unsigned short* __restrict__ A2s,
                                               unsigned char* __restrict__ H8b) {
    int wave = (blockIdx.x * 256 + threadIdx.x) >> 6;
    int lane = threadIdx.x & 63;
    int m = lane & 15, quad = lane >> 4;
    if (wave >= NSTRIPS) return;
    short8 bf[4][2];
#pragma unroll
    for (int t = 0; t < 4; t++)
#pragma unroll
        for (int s = 0; s < 2; s++)
            bf[t][s] = *(const short8*)(Bt1 + (t * 16 + m) * 64 + s * 32 + quad * 8);
    float bias[4];
#pragma unroll
    for (int t = 0; t < 4; t++) bias[t] = b1[t * 16 + m];

    int row0 = wave * 16;
    short8 a0 = *(const short8*)(A1 + (row0 + m) * 64 + quad * 8);
    short8 a1 = *(const short8*)(A1 + (row0 + m) * 64 + 32 + quad * 8);
    float4_ acc[4];
#pragma unroll
    for (int t = 0; t < 4; t++) {
        float4_ c = {0.f, 0.f, 0.f, 0.f};
        c = __builtin_amdgcn_mfma_f32_16x16x32_bf16(a0, bf[t][0], c, 0, 0, 0);
        c = __builtin_amdgcn_mfma_f32_16x16x32_bf16(a1, bf[t][1], c, 0, 0, 0);
        acc[t] = c;
    }
#pragma unroll
    for (int t = 0; t < 4; t++) {
        int col = t * 16 + m;
#pragma unroll
        for (int r = 0; r < 4; r++) {
            int row = row0 + quad * 4 + r;
            float v = fmaxf(acc[t][r] + bias[t], 0.f);
            A2s[row * 128 + 64 + col] = f2bf(v);
            H8b[row * 64 + col] =
                (unsigned char)(__builtin_amdgcn_cvt_pk_fp8_f32(v, 0.f, 0, false) & 0xFF);
        }
    }
}

__global__ __launch_bounds__(256) void k_gemm2(const unsigned short* __restrict__ Bt2,
                                               const float* __restrict__ bias2,
                                               unsigned short* A2s,
                                               float* logits) {
    int wave = (blockIdx.x * 256 + threadIdx.x) >> 6;
    int lane = threadIdx.x & 63;
    int m = lane & 15, quad = lane >> 4;
    if (wave >= NSTRIPS) return;
    short8 bf[5][4];
#pragma unroll
    for (int t = 0; t < 5; t++)
#pragma unroll
        for (int s = 0; s < 4; s++)
            bf[t][s] = *(const short8*)(Bt2 + (t * 16 + m) * 128 + s * 32 + quad * 8);
    float bias[5];
#pragma unroll
    for (int t = 0; t < 5; t++) bias[t] = bias2[t * 16 + m];

    int row0 = wave * 16;
    short8 a[4];
#pragma unroll
    for (int s = 0; s < 4; s++)
        a[s] = *(const short8*)(A2s + (row0 + m) * 128 + s * 32 + quad * 8);
    float4_ acc[5];
#pragma unroll
    for (int t = 0; t < 5; t++) {
        float4_ c = {0.f, 0.f, 0.f, 0.f};
#pragma unroll
        for (int s = 0; s < 4; s++)
            c = __builtin_amdgcn_mfma_f32_16x16x32_bf16(a[s], bf[t][s], c, 0, 0, 0);
        acc[t] = c;
    }
    float* embp = (float*)A2s;
#pragma unroll
    for (int t = 0; t < 4; t++) {
#pragma unroll
        for (int r = 0; r < 4; r++) {
            int row = row0 + quad * 4 + r;
            embp[row * 64 + t * 16 + m] = acc[t][r] + bias[t];
        }
    }
#pragma unroll
    for (int r = 0; r < 4; r++) {
        int row = row0 + quad * 4 + r;
        logits[row * 16 + m] = acc[4][r] + bias[4];
    }
}

// ---------------- launch ----------------

extern "C" void kernel_launch(void* const* d_in, const int* in_sizes, int n_in,
                              void* d_out, int out_size, void* d_ws, size_t ws_size,
                              hipStream_t stream) {
    const float* x = (const float*)d_in[0];
    const int* edge = (const int*)d_in[1];
    const int* srcIdx = edge;
    const int* dstIdx = edge + N_EDGES;
    const float* W1l = (const float*)d_in[2];
    const float* b1  = (const float*)d_in[3];
    const float* W1r = (const float*)d_in[4];
    const float* W2l = (const float*)d_in[5];
    const float* b2  = (const float*)d_in[6];
    const float* W2r = (const float*)d_in[7];
    const float* Wc  = (const float*)d_in[8];
    const float* bc  = (const float*)d_in[9];

    float* logits = (float*)d_out;
    unsigned short* A2s = (unsigned short*)((float*)d_out + (size_t)N_NODES * N_CLASSES);
    unsigned int* A2u = (unsigned int*)A2s;

    char* w = (char*)d_ws;
    auto carve = [&](size_t bytes) {
        char* p = w;
        w += (bytes + 255) & ~(size_t)255;
        return p;
    };
    int2* begend         = (int2*)carve((size_t)N_NODES * sizeof(int2));
    int* srcs            = (int*)carve((size_t)NBUCK * CAP * sizeof(int));
    unsigned int* A1u    = (unsigned int*)carve((size_t)N_NODES * 32 * sizeof(unsigned int));
    unsigned short* X8s  = (unsigned short*)carve((size_t)N_NODES * 32);   // fp8 x, 32B rows
    unsigned char* H8b   = (unsigned char*)carve((size_t)N_NODES * 64);    // fp8 h, 64B rows
    int* bucketFill      = (int*)carve(NBUCK * sizeof(int));
    unsigned short* Bt1  = (unsigned short*)carve(64 * 64 * sizeof(unsigned short));
    unsigned short* Bt2  = (unsigned short*)carve(80 * 128 * sizeof(unsigned short));
    float* bias2         = (float*)carve(80 * sizeof(float));

    // pedges (14.4 MB) aliases A1u (12.8 MB) + start of X8s; both are written
    // only AFTER k_bucket has consumed pedges
    unsigned int* pedges = (unsigned int*)A1u;
    unsigned short* A1s = (unsigned short*)A1u;
    unsigned int* X8u = (unsigned int*)X8s;
    unsigned int* H8u = (unsigned int*)H8b;

    k_prep<<<1, 256, 0, stream>>>(W1l, W1r, W2l, W2r, Wc, b2, bc, Bt1, Bt2, bias2,
                                  bucketFill);
    k_part<<<PTBLOCKS, 1024, 0, stream>>>(srcIdx, dstIdx, bucketFill, pedges);
    k_bucket<<<NBUCK, 1024, 0, stream>>>(pedges, bucketFill, begend, srcs, N_NODES);

    k_castx<<<(N_NODES * 16 + 255) / 256, 256, 0, stream>>>(x, A1u, X8s);
    int agrid = (N_NODES * 64 + 255) / 256;
    k_agg1<<<agrid, 256, 0, stream>>>(X8u, begend, srcs, A1u, N_NODES);
    k_gemm1<<<(NSTRIPS + 3) / 4, 256, 0, stream>>>(A1s, Bt1, b1, A2s, H8b);
    k_agg2<<<agrid, 256, 0, stream>>>(H8u, begend, srcs, A2u, N_NODES);
    k_gemm2<<<(NSTRIPS + 3) / 4, 256, 0, stream>>>(Bt2, bias2, A2s, logits);
}